// Round 15
// baseline (737.533 us; speedup 1.0000x reference)
//
#include <hip/hip_runtime.h>

#define NB 16
#define NPTS 4096
#define NC 64
#define NS 1024
#define NK 32

typedef float v2f __attribute__((ext_vector_type(2)));
typedef short bf16x8 __attribute__((ext_vector_type(8)));
typedef float f32x4 __attribute__((ext_vector_type(4)));

#define DPP_ROR_I(x, N) __builtin_amdgcn_update_dpp(0, (int)(x), 0x120 + (N), 0xf, 0xf, false)
#define MFMA16(a, b, c) __builtin_amdgcn_mfma_f32_16x16x32_bf16((a), (b), (c), 0, 0, 0)

static __device__ __forceinline__ float max3f(float a, float b, float c) {
    return fmaxf(fmaxf(a, b), c);
}
static __device__ __forceinline__ unsigned min3u(unsigned a, unsigned b, unsigned c) {
    const unsigned m = a < b ? a : b;
    return m < c ? m : c;
}
static __device__ __forceinline__ unsigned short f2bf(float f) {
    const unsigned u = __float_as_uint(f);
    const unsigned r = 0x7FFFu + ((u >> 16) & 1u);
    return (unsigned short)((u + r) >> 16);
}
static __device__ __forceinline__ float bf2f(unsigned short h) {
    return __uint_as_float(((unsigned)h) << 16);
}
static __device__ __forceinline__ unsigned pkhi(float a, float b) {
    return (unsigned)f2bf(a) | ((unsigned)f2bf(b) << 16);
}
static __device__ __forceinline__ unsigned pklo(float a, float b) {
    const float la = a - bf2f(f2bf(a));
    const float lb = b - bf2f(f2bf(b));
    return (unsigned)f2bf(la) | ((unsigned)f2bf(lb) << 16);
}

#define KNN_INF 3.0e38f
#define SMEM_BYTES 111168

__global__ __launch_bounds__(256) void fused_kernel(
        const float* __restrict__ xyz, const float* __restrict__ points,
        const float* __restrict__ w0, const float* __restrict__ b0,
        const float* __restrict__ w1, const float* __restrict__ b1,
        const float* __restrict__ w2, const float* __restrict__ b2,
        float* __restrict__ out, unsigned* __restrict__ progress) {
    __shared__ __align__(16) char smem[SMEM_BYTES];

    const int t = threadIdx.x;
    const int lane = t & 63;
    const int wv = t >> 6;
    float* newxyz = out;                         // (B,S,3)
    float* outpts = out + (size_t)NB * NS * 3;   // (B,S,128)

    if (blockIdx.x < NB) {
        // ================= FPS producer (R10-verified core) =================
        float4* pts = (float4*)smem;
        float* hist = (float*)(smem + 65536);             // [3][1024]
        unsigned* wk = (unsigned*)(smem + 65536 + 12288); // [2][4][2]
        const int b = blockIdx.x;

        const float* xb = xyz + (size_t)b * NPTS * 3;
        for (int i = t; i < NPTS; i += 256) {
            pts[i] = make_float4(xb[3 * i], xb[3 * i + 1], xb[3 * i + 2], 0.0f);
        }
        __syncthreads();

        v2f PX[8], PY[8], PZ[8];
        float dm[16];
#pragma unroll
        for (int k = 0; k < 8; ++k) {
            const float4 p0 = pts[t + (2 * k) * 256];
            const float4 p1 = pts[t + (2 * k + 1) * 256];
            PX[k].x = p0.x; PX[k].y = p1.x;
            PY[k].x = p0.y; PY[k].y = p1.y;
            PZ[k].x = p0.z; PZ[k].y = p1.z;
            dm[2 * k] = 1e10f; dm[2 * k + 1] = 1e10f;
        }

        const float4 c0 = pts[0];
        float cx = c0.x, cy = c0.y, cz = c0.z;
        unsigned* obu = (unsigned*)(newxyz + (size_t)b * NS * 3);

        for (int s = 0; s < NS; ++s) {
            if ((s & 15) == 0 && s > 0) {
                if (t == 0) {
                    asm volatile("s_waitcnt vmcnt(0)" ::: "memory");
                    __hip_atomic_fetch_add(&progress[b], 16u, __ATOMIC_RELAXED, __HIP_MEMORY_SCOPE_AGENT);
                }
            }
            if (t == 0) { hist[s] = cx; hist[1024 + s] = cy; hist[2048 + s] = cz; }

            const v2f cX = { cx, cx };
            const v2f cY = { cy, cy };
            const v2f cZ = { cz, cz };
#pragma unroll
            for (int k = 0; k < 8; ++k) {
                const v2f dX = PX[k] - cX;
                const v2f dY = PY[k] - cY;
                const v2f dZ = PZ[k] - cZ;
                const v2f t1 = dX * dX;
                const v2f t2 = dY * dY;
                const v2f t3 = dZ * dZ;
                const v2f ss = (t1 + t2) + t3;
                dm[2 * k] = fminf(dm[2 * k], ss.x);
                dm[2 * k + 1] = fminf(dm[2 * k + 1], ss.y);
            }

            const float ta = max3f(dm[0], dm[1], dm[2]);
            const float tb = max3f(dm[3], dm[4], dm[5]);
            const float tc = max3f(dm[6], dm[7], dm[8]);
            const float td = max3f(dm[9], dm[10], dm[11]);
            const float te = max3f(dm[12], dm[13], dm[14]);
            const float mv = fmaxf(max3f(ta, tb, tc), max3f(td, te, dm[15]));

            unsigned u[16];
#pragma unroll
            for (int j = 0; j < 16; ++j)
                u[j] = (dm[j] == mv) ? (unsigned)(t + j * 256) : 0xFFFFFFFFu;
            const unsigned ua = min3u(u[0], u[1], u[2]);
            const unsigned ub = min3u(u[3], u[4], u[5]);
            const unsigned uc = min3u(u[6], u[7], u[8]);
            const unsigned ud = min3u(u[9], u[10], u[11]);
            const unsigned ue = min3u(u[12], u[13], u[14]);
            const unsigned uf = min3u(ua, ub, uc);
            const unsigned ug = min3u(ud, ue, u[15]);
            const unsigned best = uf < ug ? uf : ug;

            float r = mv;
            { const float o = __int_as_float(DPP_ROR_I(__float_as_int(r), 1)); r = fmaxf(r, o); }
            { const float o = __int_as_float(DPP_ROR_I(__float_as_int(r), 2)); r = fmaxf(r, o); }
            { const float o = __int_as_float(DPP_ROR_I(__float_as_int(r), 4)); r = fmaxf(r, o); }
            { const float o = __int_as_float(DPP_ROR_I(__float_as_int(r), 8)); r = fmaxf(r, o); }
            const float q0 = __int_as_float(__builtin_amdgcn_readlane(__float_as_int(r), 0));
            const float q1 = __int_as_float(__builtin_amdgcn_readlane(__float_as_int(r), 16));
            const float q2 = __int_as_float(__builtin_amdgcn_readlane(__float_as_int(r), 32));
            const float q3 = __int_as_float(__builtin_amdgcn_readlane(__float_as_int(r), 48));
            const float wm = fmaxf(fmaxf(q0, q1), fmaxf(q2, q3));

            unsigned c = (mv == wm) ? best : 0xFFFFFFFFu;
            { const unsigned o = (unsigned)DPP_ROR_I(c, 1); c = o < c ? o : c; }
            { const unsigned o = (unsigned)DPP_ROR_I(c, 2); c = o < c ? o : c; }
            { const unsigned o = (unsigned)DPP_ROR_I(c, 4); c = o < c ? o : c; }
            { const unsigned o = (unsigned)DPP_ROR_I(c, 8); c = o < c ? o : c; }
            const unsigned g0v = (unsigned)__builtin_amdgcn_readlane((int)c, 0);
            const unsigned g1v = (unsigned)__builtin_amdgcn_readlane((int)c, 16);
            const unsigned g2v = (unsigned)__builtin_amdgcn_readlane((int)c, 32);
            const unsigned g3v = (unsigned)__builtin_amdgcn_readlane((int)c, 48);
            const unsigned ga = g0v < g1v ? g0v : g1v;
            const unsigned gb = g2v < g3v ? g2v : g3v;
            const unsigned wgi = ga < gb ? ga : gb;

            if (lane == 0) { wk[((s & 1) * 4 + wv) * 2] = __float_as_uint(wm); wk[((s & 1) * 4 + wv) * 2 + 1] = ~wgi; }
            __syncthreads();
            const unsigned* wb = &wk[(s & 1) * 8];
            const unsigned long long k0 = ((unsigned long long)wb[0] << 32) | wb[1];
            const unsigned long long k1 = ((unsigned long long)wb[2] << 32) | wb[3];
            const unsigned long long k2 = ((unsigned long long)wb[4] << 32) | wb[5];
            const unsigned long long k3 = ((unsigned long long)wb[6] << 32) | wb[7];
            const unsigned long long ka = k0 > k1 ? k0 : k1;
            const unsigned long long kb = k2 > k3 ? k2 : k3;
            const unsigned long long kw = ka > kb ? ka : kb;

            if ((s & 15) == 15 && t < 48) {
                const int f = (s & ~15) * 3 + t;
                __hip_atomic_store(obu + f, __float_as_uint(hist[(f % 3) * 1024 + f / 3]),
                                   __ATOMIC_RELAXED, __HIP_MEMORY_SCOPE_AGENT);
            }

            const int wi = (int)(~(unsigned)kw);
            const float4 cc = pts[wi];
            cx = cc.x; cy = cc.y; cz = cc.z;
        }
        if (t == 0) {
            asm volatile("s_waitcnt vmcnt(0)" ::: "memory");
            __hip_atomic_fetch_add(&progress[b], 16u, __ATOMIC_RELAXED, __HIP_MEMORY_SCOPE_AGENT);
        }
    } else {
        // ================= KNN + MLP consumer =================
        float* xs = (float*)smem;                 // [4096] SoA (bank-conflict-free)
        float* ys = xs + NPTS;
        float* zs = ys + NPTS;
        float* pss = zs + NPTS;
        unsigned* aHi = (unsigned*)(smem + 65536);
        unsigned* aLo = aHi + 64 * 52;
        unsigned* bHi = aLo + 64 * 52;
        unsigned* bLo = bHi + 64 * 36;
        int* sIc = (int*)(bLo + 64 * 36);      // [4][32]
        float* nqc = (float*)(sIc + 128);      // [4][3]

        const int w = blockIdx.x - NB;
        const int batch = w & 15;
        const int widx = w >> 4;               // 0..14

        const float* xb = xyz + (size_t)batch * NPTS * 3;
        for (int i = t; i < NPTS; i += 256) {
            const float x = xb[3 * i], y = xb[3 * i + 1], z = xb[3 * i + 2];
            const float ps = __fadd_rn(__fadd_rn(__fmul_rn(x, x), __fmul_rn(y, y)), __fmul_rn(z, z));
            xs[i] = x; ys[i] = y; zs[i] = z; pss[i] = ps;
        }

        const int col0 = (wv << 4) + (lane & 15);
        const int kb = (lane >> 4) << 3;

        // ---- hoisted weight fragments (loop-invariant across chunks) ----
        bf16x8 w0h[3], w0l[3];
#pragma unroll
        for (int kt = 0; kt < 3; ++kt) {
#pragma unroll
            for (int j = 0; j < 8; ++j) {
                const int k = kt * 32 + kb + j;
                const int worig = (k < 64) ? (k + 3) : ((k < 67) ? (k - 64) : -1);
                const float v = (worig >= 0) ? w0[worig * 64 + col0] : 0.0f;
                const unsigned short h = f2bf(v);
                w0h[kt][j] = (short)h;
                w0l[kt][j] = (short)f2bf(v - bf2f(h));
            }
        }
        bf16x8 w1h[2], w1l[2];
#pragma unroll
        for (int kt = 0; kt < 2; ++kt) {
#pragma unroll
            for (int j = 0; j < 8; ++j) {
                const int k = kt * 32 + kb + j;
                const float v = w1[k * 64 + col0];
                const unsigned short h = f2bf(v);
                w1h[kt][j] = (short)h;
                w1l[kt][j] = (short)f2bf(v - bf2f(h));
            }
        }
        const int colB = ((wv + 4) << 4) + (lane & 15);
        bf16x8 w2ha[2], w2la[2], w2hb[2], w2lb[2];
#pragma unroll
        for (int kt = 0; kt < 2; ++kt) {
#pragma unroll
            for (int j = 0; j < 8; ++j) {
                const int k = kt * 32 + kb + j;
                float v = w2[k * 128 + col0];
                unsigned short h = f2bf(v);
                w2ha[kt][j] = (short)h;
                w2la[kt][j] = (short)f2bf(v - bf2f(h));
                v = w2[k * 128 + colB];
                h = f2bf(v);
                w2hb[kt][j] = (short)h;
                w2lb[kt][j] = (short)f2bf(v - bf2f(h));
            }
        }
        const float bias0 = b0[col0];
        const float bias1 = b1[col0];
        const float bias2a = b2[col0];
        const float bias2b = b2[colB];
        __syncthreads();

        for (int chunk = widx; chunk < 256; chunk += 15) {
            const int s0 = chunk * 4;
            if (t == 0) {
                while (__hip_atomic_load(&progress[batch], __ATOMIC_RELAXED, __HIP_MEMORY_SCOPE_AGENT)
                       < (unsigned)(s0 + 4))
                    __builtin_amdgcn_s_sleep(16);
            }
            __syncthreads();

            // ---- KNN: one wave per query (R10-verified algorithm; SoA LDS)
            {
                const int s = s0 + wv;
                const unsigned* qp = (const unsigned*)(newxyz + ((size_t)batch * NS + s) * 3);
                const float qx = __uint_as_float(__hip_atomic_load(qp + 0, __ATOMIC_RELAXED, __HIP_MEMORY_SCOPE_AGENT));
                const float qy = __uint_as_float(__hip_atomic_load(qp + 1, __ATOMIC_RELAXED, __HIP_MEMORY_SCOPE_AGENT));
                const float qz = __uint_as_float(__hip_atomic_load(qp + 2, __ATOMIC_RELAXED, __HIP_MEMORY_SCOPE_AGENT));
                const float qs = __fadd_rn(__fadd_rn(__fmul_rn(qx, qx), __fmul_rn(qy, qy)), __fmul_rn(qz, qz));

                float v0 = KNN_INF, v1 = KNN_INF, v2 = KNN_INF, v3 = KNN_INF;
                int i0 = 0, i1 = 0, i2 = 0, i3 = 0;
                unsigned long long rem = 0ull;

#pragma unroll 4
                for (int j = 0; j < 64; ++j) {
                    const int gi = j * 64 + lane;
                    const float px = xs[gi], py = ys[gi], pz = zs[gi], pw = pss[gi];
                    const float dot = __fmaf_rn(qz, pz, __fmaf_rn(qy, py, __fmul_rn(qx, px)));
                    const float d = __fadd_rn(__fsub_rn(qs, __fadd_rn(dot, dot)), pw);
                    const bool c0 = d < v0, c1 = d < v1, c2 = d < v2, c3 = d < v3;
                    v3 = c3 ? (c2 ? v2 : d) : v3;  i3 = c3 ? (c2 ? i2 : gi) : i3;
                    v2 = c2 ? (c1 ? v1 : d) : v2;  i2 = c2 ? (c1 ? i1 : gi) : i2;
                    v1 = c1 ? (c0 ? v0 : d) : v1;  i1 = c1 ? (c0 ? i0 : gi) : i1;
                    v0 = c0 ? d : v0;              i0 = c0 ? gi : i0;
                }

                int kidx = 0;
#pragma unroll 1
                for (int r = 0; r < NK; ++r) {
                    float rv = v0;
                    { const float o = __int_as_float(DPP_ROR_I(__float_as_int(rv), 1)); rv = fminf(rv, o); }
                    { const float o = __int_as_float(DPP_ROR_I(__float_as_int(rv), 2)); rv = fminf(rv, o); }
                    { const float o = __int_as_float(DPP_ROR_I(__float_as_int(rv), 4)); rv = fminf(rv, o); }
                    { const float o = __int_as_float(DPP_ROR_I(__float_as_int(rv), 8)); rv = fminf(rv, o); }
                    const float q0v = __int_as_float(__builtin_amdgcn_readlane(__float_as_int(rv), 0));
                    const float q1v = __int_as_float(__builtin_amdgcn_readlane(__float_as_int(rv), 16));
                    const float q2v = __int_as_float(__builtin_amdgcn_readlane(__float_as_int(rv), 32));
                    const float q3v = __int_as_float(__builtin_amdgcn_readlane(__float_as_int(rv), 48));
                    const float wm = fminf(fminf(q0v, q1v), fminf(q2v, q3v));

                    unsigned cand = (v0 == wm) ? (unsigned)i0 : 0x7FFFFFFFu;
                    { const unsigned o = (unsigned)DPP_ROR_I(cand, 1); cand = o < cand ? o : cand; }
                    { const unsigned o = (unsigned)DPP_ROR_I(cand, 2); cand = o < cand ? o : cand; }
                    { const unsigned o = (unsigned)DPP_ROR_I(cand, 4); cand = o < cand ? o : cand; }
                    { const unsigned o = (unsigned)DPP_ROR_I(cand, 8); cand = o < cand ? o : cand; }
                    const unsigned c0r = (unsigned)__builtin_amdgcn_readlane((int)cand, 0);
                    const unsigned c1r = (unsigned)__builtin_amdgcn_readlane((int)cand, 16);
                    const unsigned c2r = (unsigned)__builtin_amdgcn_readlane((int)cand, 32);
                    const unsigned c3r = (unsigned)__builtin_amdgcn_readlane((int)cand, 48);
                    const unsigned ca = c0r < c1r ? c0r : c1r;
                    const unsigned cb = c2r < c3r ? c2r : c3r;
                    const int bi = (int)(ca < cb ? ca : cb);

                    if (lane == r) kidx = bi;
                    if ((bi & 63) == lane) {
                        v0 = v1; i0 = i1;
                        v1 = v2; i1 = i2;
                        v2 = v3; i2 = i3;
                        v3 = KNN_INF;
                        rem |= 1ull << (bi >> 6);
                        if (v0 >= 1e37f) {
                            v0 = v1 = v2 = v3 = KNN_INF;
#pragma unroll 1
                            for (int j = 0; j < 64; ++j) {
                                if (!((rem >> j) & 1ull)) {
                                    const int gi = j * 64 + lane;
                                    const float px = xs[gi], py = ys[gi], pz = zs[gi], pw = pss[gi];
                                    const float dot = __fmaf_rn(qz, pz, __fmaf_rn(qy, py, __fmul_rn(qx, px)));
                                    const float d = __fadd_rn(__fsub_rn(qs, __fadd_rn(dot, dot)), pw);
                                    const bool c0 = d < v0, c1 = d < v1, c2 = d < v2, c3 = d < v3;
                                    v3 = c3 ? (c2 ? v2 : d) : v3;  i3 = c3 ? (c2 ? i2 : gi) : i3;
                                    v2 = c2 ? (c1 ? v1 : d) : v2;  i2 = c2 ? (c1 ? i1 : gi) : i2;
                                    v1 = c1 ? (c0 ? v0 : d) : v1;  i1 = c1 ? (c0 ? i0 : gi) : i1;
                                    v0 = c0 ? d : v0;              i0 = c0 ? gi : i0;
                                }
                            }
                        }
                    }
                }

                if (lane < NK) sIc[wv * 32 + lane] = kidx;
                if (lane == 0) { nqc[wv * 3] = qx; nqc[wv * 3 + 1] = qy; nqc[wv * 3 + 2] = qz; }
            }

            // ---- MLP: two 2-group units (R11-verified structure, hoisted weights)
#pragma unroll 1
            for (int uu = 0; uu < 2; ++uu) {
                __syncthreads();

#pragma unroll
                for (int j = 0; j < 4; ++j) {
                    const int id = j * 256 + t;
                    const int row = id >> 4, qq = id & 15;
                    const int idx = sIc[uu * 64 + row];
                    const float4 p = *(const float4*)(points + (((size_t)batch * NPTS + idx) << 6) + qq * 4);
                    aHi[row * 52 + qq * 2]     = pkhi(p.x, p.y);
                    aHi[row * 52 + qq * 2 + 1] = pkhi(p.z, p.w);
                    aLo[row * 52 + qq * 2]     = pklo(p.x, p.y);
                    aLo[row * 52 + qq * 2 + 1] = pklo(p.z, p.w);
                }
                if (t < 64) {
                    const int row = t;
                    const int idx = sIc[uu * 64 + row];
                    const int lq = 2 * uu + (row >> 5);
                    const float dx = xs[idx] - nqc[lq * 3];
                    const float dy = ys[idx] - nqc[lq * 3 + 1];
                    const float dz = zs[idx] - nqc[lq * 3 + 2];
                    aHi[row * 52 + 32] = pkhi(dx, dy);
                    aHi[row * 52 + 33] = pkhi(dz, 0.0f);
                    aLo[row * 52 + 32] = pklo(dx, dy);
                    aLo[row * 52 + 33] = pklo(dz, 0.0f);
                }
#pragma unroll
                for (int j = 0; j < 4; ++j) {
                    const int id = j * 256 + t;
                    const int row = id >> 4, c = 34 + (id & 15);
                    aHi[row * 52 + c] = 0u;
                    aLo[row * 52 + c] = 0u;
                }
                __syncthreads();

#pragma unroll
                for (int mt = 0; mt < 4; ++mt) {
                    f32x4 acc = { bias0, bias0, bias0, bias0 };
#pragma unroll
                    for (int kt = 0; kt < 3; ++kt) {
                        const int base = (mt * 16 + (lane & 15)) * 52 + kt * 16 + ((lane >> 4) << 2);
                        const bf16x8 ah = *(const bf16x8*)&aHi[base];
                        const bf16x8 al = *(const bf16x8*)&aLo[base];
                        acc = MFMA16(ah, w0h[kt], acc);
                        acc = MFMA16(al, w0h[kt], acc);
                        acc = MFMA16(ah, w0l[kt], acc);
                    }
#pragma unroll
                    for (int r = 0; r < 4; ++r) {
                        const float v = fmaxf(acc[r], 0.0f);
                        const int row = mt * 16 + ((lane >> 4) << 2) + r;
                        const unsigned short h = f2bf(v);
                        ((unsigned short*)bHi)[row * 72 + col0] = h;
                        ((unsigned short*)bLo)[row * 72 + col0] = f2bf(v - bf2f(h));
                    }
                }
                __syncthreads();

#pragma unroll
                for (int mt = 0; mt < 4; ++mt) {
                    f32x4 acc = { bias1, bias1, bias1, bias1 };
#pragma unroll
                    for (int kt = 0; kt < 2; ++kt) {
                        const int base = (mt * 16 + (lane & 15)) * 36 + kt * 16 + ((lane >> 4) << 2);
                        const bf16x8 ah = *(const bf16x8*)&bHi[base];
                        const bf16x8 al = *(const bf16x8*)&bLo[base];
                        acc = MFMA16(ah, w1h[kt], acc);
                        acc = MFMA16(al, w1h[kt], acc);
                        acc = MFMA16(ah, w1l[kt], acc);
                    }
#pragma unroll
                    for (int r = 0; r < 4; ++r) {
                        const float v = fmaxf(acc[r], 0.0f);
                        const int row = mt * 16 + ((lane >> 4) << 2) + r;
                        const unsigned short h = f2bf(v);
                        ((unsigned short*)aHi)[row * 72 + col0] = h;
                        ((unsigned short*)aLo)[row * 72 + col0] = f2bf(v - bf2f(h));
                    }
                }
                __syncthreads();

#pragma unroll
                for (int gj = 0; gj < 2; ++gj) {
                    f32x4 aA[2], aB[2];
#pragma unroll
                    for (int hh = 0; hh < 2; ++hh) {
                        const int mt = gj * 2 + hh;
                        f32x4 accA = { bias2a, bias2a, bias2a, bias2a };
                        f32x4 accB = { bias2b, bias2b, bias2b, bias2b };
#pragma unroll
                        for (int kt = 0; kt < 2; ++kt) {
                            const int base = (mt * 16 + (lane & 15)) * 36 + kt * 16 + ((lane >> 4) << 2);
                            const bf16x8 ah = *(const bf16x8*)&aHi[base];
                            const bf16x8 al = *(const bf16x8*)&aLo[base];
                            accA = MFMA16(ah, w2ha[kt], accA);
                            accA = MFMA16(al, w2ha[kt], accA);
                            accA = MFMA16(ah, w2la[kt], accA);
                            accB = MFMA16(ah, w2hb[kt], accB);
                            accB = MFMA16(al, w2hb[kt], accB);
                            accB = MFMA16(ah, w2lb[kt], accB);
                        }
                        aA[hh] = accA;
                        aB[hh] = accB;
                    }
                    float mA = max3f(max3f(aA[0][0], aA[0][1], aA[0][2]),
                                     max3f(aA[0][3], aA[1][0], aA[1][1]),
                                     fmaxf(aA[1][2], aA[1][3]));
                    float mB = max3f(max3f(aB[0][0], aB[0][1], aB[0][2]),
                                     max3f(aB[0][3], aB[1][0], aB[1][1]),
                                     fmaxf(aB[1][2], aB[1][3]));
                    mA = fmaxf(mA, __shfl_xor(mA, 16));
                    mA = fmaxf(mA, __shfl_xor(mA, 32));
                    mB = fmaxf(mB, __shfl_xor(mB, 16));
                    mB = fmaxf(mB, __shfl_xor(mB, 32));
                    mA = fmaxf(mA, 0.0f);
                    mB = fmaxf(mB, 0.0f);
                    float* op = outpts + (size_t)((size_t)batch * NS + s0 + 2 * uu + gj) * 128;
                    if (lane < 16) {
                        op[(wv << 4) + lane] = mA;
                        op[((wv + 4) << 4) + lane] = mB;
                    }
                }
            }
        }
    }
}

extern "C" void kernel_launch(void* const* d_in, const int* in_sizes, int n_in,
                              void* d_out, int out_size, void* d_ws, size_t ws_size,
                              hipStream_t stream) {
    const float* xyz    = (const float*)d_in[0];
    const float* points = (const float*)d_in[1];
    const float* w0 = (const float*)d_in[2];
    const float* b0 = (const float*)d_in[3];
    const float* w1 = (const float*)d_in[4];
    const float* b1 = (const float*)d_in[5];
    const float* w2 = (const float*)d_in[6];
    const float* b2 = (const float*)d_in[7];

    unsigned* progress = (unsigned*)d_ws;  // 16 u32 counters
    hipMemsetAsync(progress, 0, 64, stream);

    fused_kernel<<<256, 256, 0, stream>>>(xyz, points, w0, b0, w1, b1, w2, b2,
                                          (float*)d_out, progress);
}

// Round 16
// 709.010 us; speedup vs baseline: 1.0402x; 1.0402x over previous
//
#include <hip/hip_runtime.h>

#define NB 16
#define NPTS 4096
#define NC 64
#define NS 1024
#define NK 32

typedef float v2f __attribute__((ext_vector_type(2)));
typedef short bf16x8 __attribute__((ext_vector_type(8)));
typedef float f32x4 __attribute__((ext_vector_type(4)));

#define DPP_ROR_I(x, N) __builtin_amdgcn_update_dpp(0, (int)(x), 0x120 + (N), 0xf, 0xf, false)
#define MFMA16(a, b, c) __builtin_amdgcn_mfma_f32_16x16x32_bf16((a), (b), (c), 0, 0, 0)

static __device__ __forceinline__ float max3f(float a, float b, float c) {
    return fmaxf(fmaxf(a, b), c);
}
static __device__ __forceinline__ unsigned min3u(unsigned a, unsigned b, unsigned c) {
    const unsigned m = a < b ? a : b;
    return m < c ? m : c;
}
static __device__ __forceinline__ unsigned short f2bf(float f) {
    const unsigned u = __float_as_uint(f);
    const unsigned r = 0x7FFFu + ((u >> 16) & 1u);
    return (unsigned short)((u + r) >> 16);
}
static __device__ __forceinline__ float bf2f(unsigned short h) {
    return __uint_as_float(((unsigned)h) << 16);
}
static __device__ __forceinline__ unsigned pkhi(float a, float b) {
    return (unsigned)f2bf(a) | ((unsigned)f2bf(b) << 16);
}
static __device__ __forceinline__ unsigned pklo(float a, float b) {
    const float la = a - bf2f(f2bf(a));
    const float lb = b - bf2f(f2bf(b));
    return (unsigned)f2bf(la) | ((unsigned)f2bf(lb) << 16);
}

#define KNN_INF 3.0e38f
#define SMEM_BYTES 111168

__global__ __launch_bounds__(256) void fused_kernel(
        const float* __restrict__ xyz, const float* __restrict__ points,
        const float* __restrict__ w0, const float* __restrict__ b0,
        const float* __restrict__ w1, const float* __restrict__ b1,
        const float* __restrict__ w2, const float* __restrict__ b2,
        float* __restrict__ out, unsigned* __restrict__ progress) {
    __shared__ __align__(16) char smem[SMEM_BYTES];

    const int t = threadIdx.x;
    const int lane = t & 63;
    const int wv = t >> 6;
    float* newxyz = out;                         // (B,S,3)
    float* outpts = out + (size_t)NB * NS * 3;   // (B,S,128)

    if (blockIdx.x < NB) {
        // ================= FPS producer (R10-verified core) =================
        float4* pts = (float4*)smem;
        float* hist = (float*)(smem + 65536);             // [3][1024]
        unsigned* wk = (unsigned*)(smem + 65536 + 12288); // [2][4][2]
        const int b = blockIdx.x;
        unsigned* prog = &progress[b * 16];               // own 64B line

        const float* xb = xyz + (size_t)b * NPTS * 3;
        for (int i = t; i < NPTS; i += 256) {
            pts[i] = make_float4(xb[3 * i], xb[3 * i + 1], xb[3 * i + 2], 0.0f);
        }
        __syncthreads();

        v2f PX[8], PY[8], PZ[8];
        float dm[16];
#pragma unroll
        for (int k = 0; k < 8; ++k) {
            const float4 p0 = pts[t + (2 * k) * 256];
            const float4 p1 = pts[t + (2 * k + 1) * 256];
            PX[k].x = p0.x; PX[k].y = p1.x;
            PY[k].x = p0.y; PY[k].y = p1.y;
            PZ[k].x = p0.z; PZ[k].y = p1.z;
            dm[2 * k] = 1e10f; dm[2 * k + 1] = 1e10f;
        }

        const float4 c0 = pts[0];
        float cx = c0.x, cy = c0.y, cz = c0.z;
        unsigned* obu = (unsigned*)(newxyz + (size_t)b * NS * 3);

        for (int s = 0; s < NS; ++s) {
            if (t == 0) { hist[s] = cx; hist[1024 + s] = cy; hist[2048 + s] = cz; }

            const v2f cX = { cx, cx };
            const v2f cY = { cy, cy };
            const v2f cZ = { cz, cz };
#pragma unroll
            for (int k = 0; k < 8; ++k) {
                const v2f dX = PX[k] - cX;
                const v2f dY = PY[k] - cY;
                const v2f dZ = PZ[k] - cZ;
                const v2f t1 = dX * dX;
                const v2f t2 = dY * dY;
                const v2f t3 = dZ * dZ;
                const v2f ss = (t1 + t2) + t3;
                dm[2 * k] = fminf(dm[2 * k], ss.x);
                dm[2 * k + 1] = fminf(dm[2 * k + 1], ss.y);
            }

            const float ta = max3f(dm[0], dm[1], dm[2]);
            const float tb = max3f(dm[3], dm[4], dm[5]);
            const float tc = max3f(dm[6], dm[7], dm[8]);
            const float td = max3f(dm[9], dm[10], dm[11]);
            const float te = max3f(dm[12], dm[13], dm[14]);
            const float mv = fmaxf(max3f(ta, tb, tc), max3f(td, te, dm[15]));

            unsigned u[16];
#pragma unroll
            for (int j = 0; j < 16; ++j)
                u[j] = (dm[j] == mv) ? (unsigned)(t + j * 256) : 0xFFFFFFFFu;
            const unsigned ua = min3u(u[0], u[1], u[2]);
            const unsigned ub = min3u(u[3], u[4], u[5]);
            const unsigned uc = min3u(u[6], u[7], u[8]);
            const unsigned ud = min3u(u[9], u[10], u[11]);
            const unsigned ue = min3u(u[12], u[13], u[14]);
            const unsigned uf = min3u(ua, ub, uc);
            const unsigned ug = min3u(ud, ue, u[15]);
            const unsigned best = uf < ug ? uf : ug;

            float r = mv;
            { const float o = __int_as_float(DPP_ROR_I(__float_as_int(r), 1)); r = fmaxf(r, o); }
            { const float o = __int_as_float(DPP_ROR_I(__float_as_int(r), 2)); r = fmaxf(r, o); }
            { const float o = __int_as_float(DPP_ROR_I(__float_as_int(r), 4)); r = fmaxf(r, o); }
            { const float o = __int_as_float(DPP_ROR_I(__float_as_int(r), 8)); r = fmaxf(r, o); }
            const float q0 = __int_as_float(__builtin_amdgcn_readlane(__float_as_int(r), 0));
            const float q1 = __int_as_float(__builtin_amdgcn_readlane(__float_as_int(r), 16));
            const float q2 = __int_as_float(__builtin_amdgcn_readlane(__float_as_int(r), 32));
            const float q3 = __int_as_float(__builtin_amdgcn_readlane(__float_as_int(r), 48));
            const float wm = fmaxf(fmaxf(q0, q1), fmaxf(q2, q3));

            unsigned c = (mv == wm) ? best : 0xFFFFFFFFu;
            { const unsigned o = (unsigned)DPP_ROR_I(c, 1); c = o < c ? o : c; }
            { const unsigned o = (unsigned)DPP_ROR_I(c, 2); c = o < c ? o : c; }
            { const unsigned o = (unsigned)DPP_ROR_I(c, 4); c = o < c ? o : c; }
            { const unsigned o = (unsigned)DPP_ROR_I(c, 8); c = o < c ? o : c; }
            const unsigned g0v = (unsigned)__builtin_amdgcn_readlane((int)c, 0);
            const unsigned g1v = (unsigned)__builtin_amdgcn_readlane((int)c, 16);
            const unsigned g2v = (unsigned)__builtin_amdgcn_readlane((int)c, 32);
            const unsigned g3v = (unsigned)__builtin_amdgcn_readlane((int)c, 48);
            const unsigned ga = g0v < g1v ? g0v : g1v;
            const unsigned gb = g2v < g3v ? g2v : g3v;
            const unsigned wgi = ga < gb ? ga : gb;

            if (lane == 0) { wk[((s & 1) * 4 + wv) * 2] = __float_as_uint(wm); wk[((s & 1) * 4 + wv) * 2 + 1] = ~wgi; }
            __syncthreads();
            const unsigned* wb = &wk[(s & 1) * 8];
            const unsigned long long k0 = ((unsigned long long)wb[0] << 32) | wb[1];
            const unsigned long long k1 = ((unsigned long long)wb[2] << 32) | wb[3];
            const unsigned long long k2 = ((unsigned long long)wb[4] << 32) | wb[5];
            const unsigned long long k3 = ((unsigned long long)wb[6] << 32) | wb[7];
            const unsigned long long ka = k0 > k1 ? k0 : k1;
            const unsigned long long kb = k2 > k3 ? k2 : k3;
            const unsigned long long kw = ka > kb ? ka : kb;

            // two-window publish pipeline: at s==15 (mod 16), first drain the
            // window issued 16 iterations ago (stores long retired -> free),
            // bump progress, then issue this window's stores.
            if ((s & 15) == 15) {
                if (s > 15 && t == 0) {
                    asm volatile("s_waitcnt vmcnt(0)" ::: "memory");
                    __hip_atomic_fetch_add(prog, 16u, __ATOMIC_RELAXED, __HIP_MEMORY_SCOPE_AGENT);
                }
                if (t < 48) {
                    const int f = (s & ~15) * 3 + t;
                    __hip_atomic_store(obu + f, __float_as_uint(hist[(f % 3) * 1024 + f / 3]),
                                       __ATOMIC_RELAXED, __HIP_MEMORY_SCOPE_AGENT);
                }
            }

            const int wi = (int)(~(unsigned)kw);
            const float4 cc = pts[wi];
            cx = cc.x; cy = cc.y; cz = cc.z;
        }
        // final drain: last window's stores + bump to 1024
        if (t == 0) {
            asm volatile("s_waitcnt vmcnt(0)" ::: "memory");
            __hip_atomic_fetch_add(prog, 32u, __ATOMIC_RELAXED, __HIP_MEMORY_SCOPE_AGENT);
        }
    } else {
        // ================= KNN + MLP consumer =================
        float* xs = (float*)smem;                 // [4096] SoA
        float* ys = xs + NPTS;
        float* zs = ys + NPTS;
        float* pss = zs + NPTS;
        unsigned* aHi = (unsigned*)(smem + 65536);
        unsigned* aLo = aHi + 64 * 52;
        unsigned* bHi = aLo + 64 * 52;
        unsigned* bLo = bHi + 64 * 36;
        int* sIc = (int*)(bLo + 64 * 36);      // [4][32]
        float* nqc = (float*)(sIc + 128);      // [4][3]

        const int w = blockIdx.x - NB;
        const int batch = w & 15;
        const int widx = w >> 4;               // 0..14
        unsigned* prog = &progress[batch * 16];

        const float* xb = xyz + (size_t)batch * NPTS * 3;
        for (int i = t; i < NPTS; i += 256) {
            const float x = xb[3 * i], y = xb[3 * i + 1], z = xb[3 * i + 2];
            const float ps = __fadd_rn(__fadd_rn(__fmul_rn(x, x), __fmul_rn(y, y)), __fmul_rn(z, z));
            xs[i] = x; ys[i] = y; zs[i] = z; pss[i] = ps;
        }

        const int col0 = (wv << 4) + (lane & 15);
        const int kb = (lane >> 4) << 3;

        // hoisted weight fragments (loop-invariant)
        bf16x8 w0h[3], w0l[3];
#pragma unroll
        for (int kt = 0; kt < 3; ++kt) {
#pragma unroll
            for (int j = 0; j < 8; ++j) {
                const int k = kt * 32 + kb + j;
                const int worig = (k < 64) ? (k + 3) : ((k < 67) ? (k - 64) : -1);
                const float v = (worig >= 0) ? w0[worig * 64 + col0] : 0.0f;
                const unsigned short h = f2bf(v);
                w0h[kt][j] = (short)h;
                w0l[kt][j] = (short)f2bf(v - bf2f(h));
            }
        }
        bf16x8 w1h[2], w1l[2];
#pragma unroll
        for (int kt = 0; kt < 2; ++kt) {
#pragma unroll
            for (int j = 0; j < 8; ++j) {
                const int k = kt * 32 + kb + j;
                const float v = w1[k * 64 + col0];
                const unsigned short h = f2bf(v);
                w1h[kt][j] = (short)h;
                w1l[kt][j] = (short)f2bf(v - bf2f(h));
            }
        }
        const int colB = ((wv + 4) << 4) + (lane & 15);
        bf16x8 w2ha[2], w2la[2], w2hb[2], w2lb[2];
#pragma unroll
        for (int kt = 0; kt < 2; ++kt) {
#pragma unroll
            for (int j = 0; j < 8; ++j) {
                const int k = kt * 32 + kb + j;
                float v = w2[k * 128 + col0];
                unsigned short h = f2bf(v);
                w2ha[kt][j] = (short)h;
                w2la[kt][j] = (short)f2bf(v - bf2f(h));
                v = w2[k * 128 + colB];
                h = f2bf(v);
                w2hb[kt][j] = (short)h;
                w2lb[kt][j] = (short)f2bf(v - bf2f(h));
            }
        }
        const float bias0 = b0[col0];
        const float bias1 = b1[col0];
        const float bias2a = b2[col0];
        const float bias2b = b2[colB];
        __syncthreads();

        for (int chunk = widx; chunk < 256; chunk += 15) {
            const int s0 = chunk * 4;
            if (t == 0) {
                while (__hip_atomic_load(prog, __ATOMIC_RELAXED, __HIP_MEMORY_SCOPE_AGENT)
                       < (unsigned)(s0 + 4))
                    __builtin_amdgcn_s_sleep(127);
            }
            __syncthreads();

            // ---- KNN: one wave per query (R10-verified algorithm; SoA LDS)
            {
                const int s = s0 + wv;
                const unsigned* qp = (const unsigned*)(newxyz + ((size_t)batch * NS + s) * 3);
                const float qx = __uint_as_float(__hip_atomic_load(qp + 0, __ATOMIC_RELAXED, __HIP_MEMORY_SCOPE_AGENT));
                const float qy = __uint_as_float(__hip_atomic_load(qp + 1, __ATOMIC_RELAXED, __HIP_MEMORY_SCOPE_AGENT));
                const float qz = __uint_as_float(__hip_atomic_load(qp + 2, __ATOMIC_RELAXED, __HIP_MEMORY_SCOPE_AGENT));
                const float qs = __fadd_rn(__fadd_rn(__fmul_rn(qx, qx), __fmul_rn(qy, qy)), __fmul_rn(qz, qz));

                float v0 = KNN_INF, v1 = KNN_INF, v2 = KNN_INF, v3 = KNN_INF;
                int i0 = 0, i1 = 0, i2 = 0, i3 = 0;
                unsigned long long rem = 0ull;

#pragma unroll 4
                for (int j = 0; j < 64; ++j) {
                    const int gi = j * 64 + lane;
                    const float px = xs[gi], py = ys[gi], pz = zs[gi], pw = pss[gi];
                    const float dot = __fmaf_rn(qz, pz, __fmaf_rn(qy, py, __fmul_rn(qx, px)));
                    const float d = __fadd_rn(__fsub_rn(qs, __fadd_rn(dot, dot)), pw);
                    const bool c0 = d < v0, c1 = d < v1, c2 = d < v2, c3 = d < v3;
                    v3 = c3 ? (c2 ? v2 : d) : v3;  i3 = c3 ? (c2 ? i2 : gi) : i3;
                    v2 = c2 ? (c1 ? v1 : d) : v2;  i2 = c2 ? (c1 ? i1 : gi) : i2;
                    v1 = c1 ? (c0 ? v0 : d) : v1;  i1 = c1 ? (c0 ? i0 : gi) : i1;
                    v0 = c0 ? d : v0;              i0 = c0 ? gi : i0;
                }

                int kidx = 0;
#pragma unroll 1
                for (int r = 0; r < NK; ++r) {
                    float rv = v0;
                    { const float o = __int_as_float(DPP_ROR_I(__float_as_int(rv), 1)); rv = fminf(rv, o); }
                    { const float o = __int_as_float(DPP_ROR_I(__float_as_int(rv), 2)); rv = fminf(rv, o); }
                    { const float o = __int_as_float(DPP_ROR_I(__float_as_int(rv), 4)); rv = fminf(rv, o); }
                    { const float o = __int_as_float(DPP_ROR_I(__float_as_int(rv), 8)); rv = fminf(rv, o); }
                    const float q0v = __int_as_float(__builtin_amdgcn_readlane(__float_as_int(rv), 0));
                    const float q1v = __int_as_float(__builtin_amdgcn_readlane(__float_as_int(rv), 16));
                    const float q2v = __int_as_float(__builtin_amdgcn_readlane(__float_as_int(rv), 32));
                    const float q3v = __int_as_float(__builtin_amdgcn_readlane(__float_as_int(rv), 48));
                    const float wm = fminf(fminf(q0v, q1v), fminf(q2v, q3v));

                    unsigned cand = (v0 == wm) ? (unsigned)i0 : 0x7FFFFFFFu;
                    { const unsigned o = (unsigned)DPP_ROR_I(cand, 1); cand = o < cand ? o : cand; }
                    { const unsigned o = (unsigned)DPP_ROR_I(cand, 2); cand = o < cand ? o : cand; }
                    { const unsigned o = (unsigned)DPP_ROR_I(cand, 4); cand = o < cand ? o : cand; }
                    { const unsigned o = (unsigned)DPP_ROR_I(cand, 8); cand = o < cand ? o : cand; }
                    const unsigned c0r = (unsigned)__builtin_amdgcn_readlane((int)cand, 0);
                    const unsigned c1r = (unsigned)__builtin_amdgcn_readlane((int)cand, 16);
                    const unsigned c2r = (unsigned)__builtin_amdgcn_readlane((int)cand, 32);
                    const unsigned c3r = (unsigned)__builtin_amdgcn_readlane((int)cand, 48);
                    const unsigned ca = c0r < c1r ? c0r : c1r;
                    const unsigned cb = c2r < c3r ? c2r : c3r;
                    const int bi = (int)(ca < cb ? ca : cb);

                    if (lane == r) kidx = bi;
                    if ((bi & 63) == lane) {
                        v0 = v1; i0 = i1;
                        v1 = v2; i1 = i2;
                        v2 = v3; i2 = i3;
                        v3 = KNN_INF;
                        rem |= 1ull << (bi >> 6);
                        if (v0 >= 1e37f) {
                            v0 = v1 = v2 = v3 = KNN_INF;
#pragma unroll 1
                            for (int j = 0; j < 64; ++j) {
                                if (!((rem >> j) & 1ull)) {
                                    const int gi = j * 64 + lane;
                                    const float px = xs[gi], py = ys[gi], pz = zs[gi], pw = pss[gi];
                                    const float dot = __fmaf_rn(qz, pz, __fmaf_rn(qy, py, __fmul_rn(qx, px)));
                                    const float d = __fadd_rn(__fsub_rn(qs, __fadd_rn(dot, dot)), pw);
                                    const bool c0 = d < v0, c1 = d < v1, c2 = d < v2, c3 = d < v3;
                                    v3 = c3 ? (c2 ? v2 : d) : v3;  i3 = c3 ? (c2 ? i2 : gi) : i3;
                                    v2 = c2 ? (c1 ? v1 : d) : v2;  i2 = c2 ? (c1 ? i1 : gi) : i2;
                                    v1 = c1 ? (c0 ? v0 : d) : v1;  i1 = c1 ? (c0 ? i0 : gi) : i1;
                                    v0 = c0 ? d : v0;              i0 = c0 ? gi : i0;
                                }
                            }
                        }
                    }
                }

                if (lane < NK) sIc[wv * 32 + lane] = kidx;
                if (lane == 0) { nqc[wv * 3] = qx; nqc[wv * 3 + 1] = qy; nqc[wv * 3 + 2] = qz; }
            }

            // ---- MLP: two 2-group units (R11-verified structure)
#pragma unroll 1
            for (int uu = 0; uu < 2; ++uu) {
                __syncthreads();

#pragma unroll
                for (int j = 0; j < 4; ++j) {
                    const int id = j * 256 + t;
                    const int row = id >> 4, qq = id & 15;
                    const int idx = sIc[uu * 64 + row];
                    const float4 p = *(const float4*)(points + (((size_t)batch * NPTS + idx) << 6) + qq * 4);
                    aHi[row * 52 + qq * 2]     = pkhi(p.x, p.y);
                    aHi[row * 52 + qq * 2 + 1] = pkhi(p.z, p.w);
                    aLo[row * 52 + qq * 2]     = pklo(p.x, p.y);
                    aLo[row * 52 + qq * 2 + 1] = pklo(p.z, p.w);
                }
                if (t < 64) {
                    const int row = t;
                    const int idx = sIc[uu * 64 + row];
                    const int lq = 2 * uu + (row >> 5);
                    const float dx = xs[idx] - nqc[lq * 3];
                    const float dy = ys[idx] - nqc[lq * 3 + 1];
                    const float dz = zs[idx] - nqc[lq * 3 + 2];
                    aHi[row * 52 + 32] = pkhi(dx, dy);
                    aHi[row * 52 + 33] = pkhi(dz, 0.0f);
                    aLo[row * 52 + 32] = pklo(dx, dy);
                    aLo[row * 52 + 33] = pklo(dz, 0.0f);
                }
#pragma unroll
                for (int j = 0; j < 4; ++j) {
                    const int id = j * 256 + t;
                    const int row = id >> 4, c = 34 + (id & 15);
                    aHi[row * 52 + c] = 0u;
                    aLo[row * 52 + c] = 0u;
                }
                __syncthreads();

#pragma unroll
                for (int mt = 0; mt < 4; ++mt) {
                    f32x4 acc = { bias0, bias0, bias0, bias0 };
#pragma unroll
                    for (int kt = 0; kt < 3; ++kt) {
                        const int base = (mt * 16 + (lane & 15)) * 52 + kt * 16 + ((lane >> 4) << 2);
                        const bf16x8 ah = *(const bf16x8*)&aHi[base];
                        const bf16x8 al = *(const bf16x8*)&aLo[base];
                        acc = MFMA16(ah, w0h[kt], acc);
                        acc = MFMA16(al, w0h[kt], acc);
                        acc = MFMA16(ah, w0l[kt], acc);
                    }
#pragma unroll
                    for (int r = 0; r < 4; ++r) {
                        const float v = fmaxf(acc[r], 0.0f);
                        const int row = mt * 16 + ((lane >> 4) << 2) + r;
                        const unsigned short h = f2bf(v);
                        ((unsigned short*)bHi)[row * 72 + col0] = h;
                        ((unsigned short*)bLo)[row * 72 + col0] = f2bf(v - bf2f(h));
                    }
                }
                __syncthreads();

#pragma unroll
                for (int mt = 0; mt < 4; ++mt) {
                    f32x4 acc = { bias1, bias1, bias1, bias1 };
#pragma unroll
                    for (int kt = 0; kt < 2; ++kt) {
                        const int base = (mt * 16 + (lane & 15)) * 36 + kt * 16 + ((lane >> 4) << 2);
                        const bf16x8 ah = *(const bf16x8*)&bHi[base];
                        const bf16x8 al = *(const bf16x8*)&bLo[base];
                        acc = MFMA16(ah, w1h[kt], acc);
                        acc = MFMA16(al, w1h[kt], acc);
                        acc = MFMA16(ah, w1l[kt], acc);
                    }
#pragma unroll
                    for (int r = 0; r < 4; ++r) {
                        const float v = fmaxf(acc[r], 0.0f);
                        const int row = mt * 16 + ((lane >> 4) << 2) + r;
                        const unsigned short h = f2bf(v);
                        ((unsigned short*)aHi)[row * 72 + col0] = h;
                        ((unsigned short*)aLo)[row * 72 + col0] = f2bf(v - bf2f(h));
                    }
                }
                __syncthreads();

#pragma unroll
                for (int gj = 0; gj < 2; ++gj) {
                    f32x4 aA[2], aB[2];
#pragma unroll
                    for (int hh = 0; hh < 2; ++hh) {
                        const int mt = gj * 2 + hh;
                        f32x4 accA = { bias2a, bias2a, bias2a, bias2a };
                        f32x4 accB = { bias2b, bias2b, bias2b, bias2b };
#pragma unroll
                        for (int kt = 0; kt < 2; ++kt) {
                            const int base = (mt * 16 + (lane & 15)) * 36 + kt * 16 + ((lane >> 4) << 2);
                            const bf16x8 ah = *(const bf16x8*)&aHi[base];
                            const bf16x8 al = *(const bf16x8*)&aLo[base];
                            accA = MFMA16(ah, w2ha[kt], accA);
                            accA = MFMA16(al, w2ha[kt], accA);
                            accA = MFMA16(ah, w2la[kt], accA);
                            accB = MFMA16(ah, w2hb[kt], accB);
                            accB = MFMA16(al, w2hb[kt], accB);
                            accB = MFMA16(ah, w2lb[kt], accB);
                        }
                        aA[hh] = accA;
                        aB[hh] = accB;
                    }
                    float mA = max3f(max3f(aA[0][0], aA[0][1], aA[0][2]),
                                     max3f(aA[0][3], aA[1][0], aA[1][1]),
                                     fmaxf(aA[1][2], aA[1][3]));
                    float mB = max3f(max3f(aB[0][0], aB[0][1], aB[0][2]),
                                     max3f(aB[0][3], aB[1][0], aB[1][1]),
                                     fmaxf(aB[1][2], aB[1][3]));
                    mA = fmaxf(mA, __shfl_xor(mA, 16));
                    mA = fmaxf(mA, __shfl_xor(mA, 32));
                    mB = fmaxf(mB, __shfl_xor(mB, 16));
                    mB = fmaxf(mB, __shfl_xor(mB, 32));
                    mA = fmaxf(mA, 0.0f);
                    mB = fmaxf(mB, 0.0f);
                    float* op = outpts + (size_t)((size_t)batch * NS + s0 + 2 * uu + gj) * 128;
                    if (lane < 16) {
                        op[(wv << 4) + lane] = mA;
                        op[((wv + 4) << 4) + lane] = mB;
                    }
                }
            }
        }
    }
}

extern "C" void kernel_launch(void* const* d_in, const int* in_sizes, int n_in,
                              void* d_out, int out_size, void* d_ws, size_t ws_size,
                              hipStream_t stream) {
    const float* xyz    = (const float*)d_in[0];
    const float* points = (const float*)d_in[1];
    const float* w0 = (const float*)d_in[2];
    const float* b0 = (const float*)d_in[3];
    const float* w1 = (const float*)d_in[4];
    const float* b1 = (const float*)d_in[5];
    const float* w2 = (const float*)d_in[6];
    const float* b2 = (const float*)d_in[7];

    unsigned* progress = (unsigned*)d_ws;  // 16 counters, one 64B line each
    hipMemsetAsync(progress, 0, 1024, stream);

    fused_kernel<<<256, 256, 0, stream>>>(xyz, points, w0, b0, w1, b1, w2, b2,
                                          (float*)d_out, progress);
}